// Round 1
// baseline (545.152 us; speedup 1.0000x reference)
//
#include <hip/hip_runtime.h>
#include <math.h>

#define NB 8
#define NN 2048
#define DD 64

// ---------------- Kernel 1: h = relu(relu(x@W1+b1)@W2+b2); sq = |h|^2 ----------------
__global__ __launch_bounds__(256) void k_embed(
    const float* __restrict__ x, const float* __restrict__ W1, const float* __restrict__ b1,
    const float* __restrict__ W2, const float* __restrict__ b2,
    float* __restrict__ h, float* __restrict__ sqv)
{
    __shared__ float w2s[64 * 64];
    __shared__ float h1s[4][64];
    int tid = threadIdx.x;
    for (int q = tid; q < 4096; q += 256) w2s[q] = W2[q];
    int wave = tid >> 6, lane = tid & 63;
    int node = blockIdx.x * 4 + wave;
    const float* xr = x + node * 4;
    float x0 = xr[0], x1 = xr[1], x2 = xr[2], x3 = xr[3];
    float a = b1[lane] + x0 * W1[lane] + x1 * W1[64 + lane] + x2 * W1[128 + lane] + x3 * W1[192 + lane];
    a = fmaxf(a, 0.f);
    h1s[wave][lane] = a;
    __syncthreads();
    float acc = b2[lane];
    #pragma unroll 8
    for (int k = 0; k < 64; k++) acc += h1s[wave][k] * w2s[k * 64 + lane];
    acc = fmaxf(acc, 0.f);
    h[(long)node * 64 + lane] = acc;
    float s = acc * acc;
    #pragma unroll
    for (int m = 1; m < 64; m <<= 1) s += __shfl_xor(s, m, 64);
    if (lane == 0) sqv[node] = s;
}

// ---------------- Kernel 2: 3-NN per node (excluding self) ----------------
// block: 32 i-nodes, 256 threads; thread = (i_local = tid>>3, j_lane = tid&7)
// LDS j-tile of 64 rows, row stride 68 floats (bank-conflict pad).
#define JSTRIDE 68
__global__ __launch_bounds__(256) void k_knn(
    const float* __restrict__ h, const float* __restrict__ sqv, int* __restrict__ knn)
{
    __shared__ __align__(16) float hjt[64 * JSTRIDE];
    __shared__ float sqt[64];
    __shared__ float mval[32 * 32];
    __shared__ int   midx[32 * 32];

    int tid = threadIdx.x;
    int b = blockIdx.x >> 6;       // 64 i-tiles per batch
    int itile = blockIdx.x & 63;
    int il = tid >> 3;             // 0..31
    int jl = tid & 7;              // 0..7
    int i_in_b = itile * 32 + il;
    long gi = (long)b * NN + i_in_b;

    float4 hi4[16];
    const float4* hrow = reinterpret_cast<const float4*>(h + gi * 64);
    #pragma unroll
    for (int q = 0; q < 16; q++) hi4[q] = hrow[q];
    float sqi = sqv[gi];

    float val[4] = {3.4e38f, 3.4e38f, 3.4e38f, 3.4e38f};
    int   idx[4] = {0x7fffffff, 0x7fffffff, 0x7fffffff, 0x7fffffff};

    const float4* hb4 = reinterpret_cast<const float4*>(h + (long)b * NN * 64);
    const float* sqb = sqv + (long)b * NN;

    for (int jt = 0; jt < NN; jt += 64) {
        // stage 64 rows = 1024 float4, padded row stride
        const float4* src = hb4 + jt * 16;
        #pragma unroll
        for (int q = 0; q < 4; q++) {
            int li = q * 256 + tid;          // 0..1023
            int row = li >> 4, col = li & 15;
            *reinterpret_cast<float4*>(hjt + row * JSTRIDE + col * 4) = src[li];
        }
        if (tid < 64) sqt[tid] = sqb[jt + tid];
        __syncthreads();

        #pragma unroll
        for (int it = 0; it < 8; it++) {
            int jj = jl + it * 8;
            const float4* hj = reinterpret_cast<const float4*>(hjt + jj * JSTRIDE);
            float dot = 0.f;
            #pragma unroll
            for (int q = 0; q < 16; q++) {
                float4 a = hi4[q], bb = hj[q];
                dot += a.x * bb.x + a.y * bb.y + a.z * bb.z + a.w * bb.w;
            }
            float d = sqi + sqt[jj] - 2.f * dot;
            int j = jt + jj;
            if (d < val[3] || (d == val[3] && j < idx[3])) {
                #pragma unroll
                for (int k = 0; k < 4; k++) {
                    if (d < val[k] || (d == val[k] && j < idx[k])) {
                        for (int m = 3; m > k; m--) { val[m] = val[m-1]; idx[m] = idx[m-1]; }
                        val[k] = d; idx[k] = j;
                        break;
                    }
                }
            }
        }
        __syncthreads();
    }

    // merge the 8 per-thread top-4 lists for each i
    #pragma unroll
    for (int k = 0; k < 4; k++) {
        mval[il * 32 + jl * 4 + k] = val[k];
        midx[il * 32 + jl * 4 + k] = idx[k];
    }
    __syncthreads();
    if (jl == 0) {
        float fv[4] = {3.4e38f, 3.4e38f, 3.4e38f, 3.4e38f};
        int   fi[4] = {0x7fffffff, 0x7fffffff, 0x7fffffff, 0x7fffffff};
        for (int t = 0; t < 32; t++) {
            float d = mval[il * 32 + t];
            int j = midx[il * 32 + t];
            if (d < fv[3] || (d == fv[3] && j < fi[3])) {
                #pragma unroll
                for (int k = 0; k < 4; k++) {
                    if (d < fv[k] || (d == fv[k] && j < fi[k])) {
                        for (int m = 3; m > k; m--) { fv[m] = fv[m-1]; fi[m] = fi[m-1]; }
                        fv[k] = d; fi[k] = j;
                        break;
                    }
                }
            }
        }
        int* o = knn + gi * 3;     // drop entry 0 (self)
        o[0] = fi[1]; o[1] = fi[2]; o[2] = fi[3];
    }
}

// ---------------- Kernel 3: msgs -> concat -> u1 -> u2 -> heads ----------------
// block: 256 threads = 4 waves; each wave processes 4 nodes simultaneously.
__global__ __launch_bounds__(256) void k_head(
    const float* __restrict__ h, const int* __restrict__ knn,
    const float* __restrict__ Wm, const float* __restrict__ bm,
    const float* __restrict__ Wu1, const float* __restrict__ bu1,
    const float* __restrict__ Wu2, const float* __restrict__ bu2,
    const float* __restrict__ Wmean, const float* __restrict__ bmean,
    const float* __restrict__ Wv, const float* __restrict__ bv,
    const float* __restrict__ log_std,
    float* __restrict__ out_mean, float* __restrict__ out_std, float* __restrict__ out_val)
{
    __shared__ __align__(16) float neigh[4][4 * 3 * 64];  // 12 KB
    __shared__ float hc[4][4][128];                        // 8 KB
    __shared__ float ub[4][4][128];                        // 8 KB

    int tid = threadIdx.x;
    int wave = tid >> 6, lane = tid & 63;
    int base = blockIdx.x * 16 + wave * 4;

    // gather 4 nodes x 3 neighbors x 64 floats = 192 float4
    #pragma unroll
    for (int it = 0; it < 3; it++) {
        int q = lane + it * 64;            // 0..191
        int nl = q / 48, rem = q % 48;
        int nb = rem / 16, k4 = rem % 16;
        int node = base + nl;
        int bt = node >> 11;
        int j = knn[node * 3 + nb];
        const float4* src = reinterpret_cast<const float4*>(h + ((long)(bt << 11) + j) * 64);
        reinterpret_cast<float4*>(&neigh[wave][(nl * 3 + nb) * 64])[k4] = src[k4];
    }
    // own h into hc[.][.][0..63]
    #pragma unroll
    for (int it = 0; it < 4; it++) {
        int q = lane + it * 64;
        int nl = q >> 6, k = q & 63;
        hc[wave][nl][k] = h[(long)(base + nl) * 64 + k];
    }
    __syncthreads();

    // msgs: lane = output feature f
    float accm[4][3];
    {
        float bmf = bm[lane];
        #pragma unroll
        for (int nl = 0; nl < 4; nl++)
            #pragma unroll
            for (int e = 0; e < 3; e++) accm[nl][e] = bmf;
        for (int k = 0; k < 64; k++) {
            float w = Wm[k * 64 + lane];
            #pragma unroll
            for (int nl = 0; nl < 4; nl++)
                #pragma unroll
                for (int e = 0; e < 3; e++)
                    accm[nl][e] += neigh[wave][(nl * 3 + e) * 64 + k] * w;
        }
        #pragma unroll
        for (int nl = 0; nl < 4; nl++) {
            float m = (fmaxf(accm[nl][0], 0.f) + fmaxf(accm[nl][1], 0.f) + fmaxf(accm[nl][2], 0.f)) * (1.f / 3.f);
            hc[wave][nl][64 + lane] = m;
        }
    }
    __syncthreads();

    // u1 = relu(hc @ Wu1 + bu1): lane covers features lane and lane+64
    {
        float a0[4], a1[4];
        float b0 = bu1[lane], b1v = bu1[64 + lane];
        #pragma unroll
        for (int nl = 0; nl < 4; nl++) { a0[nl] = b0; a1[nl] = b1v; }
        for (int k = 0; k < 128; k++) {
            float w0 = Wu1[k * 128 + lane];
            float w1 = Wu1[k * 128 + 64 + lane];
            #pragma unroll
            for (int nl = 0; nl < 4; nl++) {
                float v = hc[wave][nl][k];
                a0[nl] += v * w0; a1[nl] += v * w1;
            }
        }
        #pragma unroll
        for (int nl = 0; nl < 4; nl++) {
            ub[wave][nl][lane]      = fmaxf(a0[nl], 0.f);
            ub[wave][nl][64 + lane] = fmaxf(a1[nl], 0.f);
        }
    }
    __syncthreads();

    // u2 = relu(u1 @ Wu2 + bu2) kept in registers
    float u20[4], u21[4];
    {
        float b0 = bu2[lane], b1v = bu2[64 + lane];
        #pragma unroll
        for (int nl = 0; nl < 4; nl++) { u20[nl] = b0; u21[nl] = b1v; }
        for (int k = 0; k < 128; k++) {
            float w0 = Wu2[k * 128 + lane];
            float w1 = Wu2[k * 128 + 64 + lane];
            #pragma unroll
            for (int nl = 0; nl < 4; nl++) {
                float v = ub[wave][nl][k];
                u20[nl] += v * w0; u21[nl] += v * w1;
            }
        }
        #pragma unroll
        for (int nl = 0; nl < 4; nl++) { u20[nl] = fmaxf(u20[nl], 0.f); u21[nl] = fmaxf(u21[nl], 0.f); }
    }

    // heads: mean (2), value (1) via wave reductions
    float wm0a = Wmean[lane * 2 + 0], wm0b = Wmean[(64 + lane) * 2 + 0];
    float wm1a = Wmean[lane * 2 + 1], wm1b = Wmean[(64 + lane) * 2 + 1];
    float wva  = Wv[lane],            wvb  = Wv[64 + lane];
    #pragma unroll
    for (int nl = 0; nl < 4; nl++) {
        float p0 = u20[nl] * wm0a + u21[nl] * wm0b;
        float p1 = u20[nl] * wm1a + u21[nl] * wm1b;
        float p2 = u20[nl] * wva  + u21[nl] * wvb;
        #pragma unroll
        for (int m = 1; m < 64; m <<= 1) {
            p0 += __shfl_xor(p0, m, 64);
            p1 += __shfl_xor(p1, m, 64);
            p2 += __shfl_xor(p2, m, 64);
        }
        if (lane == 0) {
            int node = base + nl;
            out_mean[node * 2 + 0] = p0 + bmean[0];
            out_mean[node * 2 + 1] = p1 + bmean[1];
            out_val[node] = p2 + bv[0];
        }
    }
    if (blockIdx.x == 0 && tid < 2) out_std[tid] = expf(log_std[tid]);
}

extern "C" void kernel_launch(void* const* d_in, const int* in_sizes, int n_in,
                              void* d_out, int out_size, void* d_ws, size_t ws_size,
                              hipStream_t stream) {
    const float* x     = (const float*)d_in[0];
    const float* W1    = (const float*)d_in[1];
    const float* b1    = (const float*)d_in[2];
    const float* W2    = (const float*)d_in[3];
    const float* b2    = (const float*)d_in[4];
    const float* Wm    = (const float*)d_in[5];
    const float* bm    = (const float*)d_in[6];
    const float* Wu1   = (const float*)d_in[7];
    const float* bu1   = (const float*)d_in[8];
    const float* Wu2   = (const float*)d_in[9];
    const float* bu2   = (const float*)d_in[10];
    const float* Wmean = (const float*)d_in[11];
    const float* bmean = (const float*)d_in[12];
    const float* Wv    = (const float*)d_in[13];
    const float* bv    = (const float*)d_in[14];
    const float* lstd  = (const float*)d_in[15];

    float* out = (float*)d_out;
    float* out_mean = out;                 // 8*2048*2 = 32768
    float* out_std  = out + 32768;         // 2
    float* out_val  = out + 32770;         // 8*2048

    float* h   = (float*)d_ws;             // 16384*64 floats
    float* sqv = h + (long)16384 * 64;     // 16384 floats
    int*   knn = (int*)(sqv + 16384);      // 16384*3 ints

    k_embed<<<4096, 256, 0, stream>>>(x, W1, b1, W2, b2, h, sqv);
    k_knn<<<512, 256, 0, stream>>>(h, sqv, knn);
    k_head<<<1024, 256, 0, stream>>>(h, knn, Wm, bm, Wu1, bu1, Wu2, bu2,
                                     Wmean, bmean, Wv, bv, lstd,
                                     out_mean, out_std, out_val);
}